// Round 1
// baseline (686.110 us; speedup 1.0000x reference)
//
#include <hip/hip_runtime.h>
#include <stdint.h>

typedef __bf16 bf16x8 __attribute__((ext_vector_type(8)));
typedef float f32x16 __attribute__((ext_vector_type(16)));

#define NN 4096
#define FF 64
#define BM 64
#define BK 128
#define NSTEP (NN / BK)  // 32

// round-to-nearest-even fp32 -> bf16
__device__ __forceinline__ unsigned short f2bf(float x) {
    unsigned int u = __builtin_bit_cast(unsigned int, x);
    unsigned int r = u + 0x7fffu + ((u >> 16) & 1u);
    return (unsigned short)(r >> 16);
}

// Pass 1: ann[b][m][f] fp32 -> annT[b][f][m] bf16 (LDS-tiled transpose)
__global__ __launch_bounds__(256) void annT_kernel(const float* __restrict__ ann,
                                                   unsigned short* __restrict__ annT) {
    __shared__ unsigned short tile[FF * 66];  // stride 66 -> 2-way (free) bank aliasing
    int b = blockIdx.x >> 6;          // 0..7
    int m0 = (blockIdx.x & 63) << 6;  // 64-row m tile
    int t = threadIdx.x;
    int f = t & 63;
    int ml = t >> 6;  // 0..3
    const float* src = ann + ((size_t)(b * NN + m0)) * FF;
#pragma unroll
    for (int it = 0; it < 16; ++it) {
        int m = it * 4 + ml;
        tile[f * 66 + m] = f2bf(src[(size_t)m * FF + f]);  // coalesced read over f
    }
    __syncthreads();
    int m2 = (t & 31) * 2;
    int fr = t >> 5;  // 0..7
    unsigned short* dst = annT + (size_t)b * FF * NN + m0;
#pragma unroll
    for (int it = 0; it < 8; ++it) {
        int fo = it * 8 + fr;
        unsigned int lo = tile[fo * 66 + m2];
        unsigned int hi = tile[fo * 66 + m2 + 1];
        *(unsigned int*)(dst + (size_t)fo * NN + m2) = lo | (hi << 16);  // coalesced write over m
    }
}

// Pass 2: out[b][n][f] = A[b][n][:] . ann[b][:][f] + bias[f]
__global__ __launch_bounds__(256, 2) void gconv_kernel(const float* __restrict__ A,
                                                       const unsigned short* __restrict__ annT,
                                                       const float* __restrict__ bias,
                                                       float* __restrict__ out) {
    __shared__ unsigned short sA[2][BM * BK];  // 16 KB each, XOR-swizzled
    __shared__ unsigned short sB[2][FF * BK];  // 16 KB each, XOR-swizzled

    // XCD swizzle: batch == blockIdx.x % 8 -> each XCD's L2 keeps one batch's annT hot
    int bi = blockIdx.x;
    int lw = (bi & 7) * 64 + (bi >> 3);
    int b = lw >> 6;           // 0..7
    int n0 = (lw & 63) << 6;   // row tile base

    int t = threadIdx.x;
    int lane = t & 63;
    int wid = t >> 6;   // 0..3
    int wm = wid >> 1;  // row half
    int wf = wid & 1;   // f half

    const float* Ab = A + (size_t)b * NN * NN + (size_t)n0 * NN;
    const unsigned short* Tb = annT + (size_t)b * FF * NN;

    float4 ra[8];  // A staging: 64x128 fp32 = 2048 float4 / 256 thr = 8
    uint4 rb[4];   // annT staging: 64x128 bf16 = 1024 uint4 / 256 thr = 4

    auto loadTiles = [&](int s) {
        int k0 = s * BK;
#pragma unroll
        for (int i = 0; i < 8; ++i) {
            int idx = i * 256 + t;
            int row = idx >> 5, c4 = idx & 31;  // 32 float4 per row
            ra[i] = *(const float4*)(Ab + (size_t)row * NN + k0 + c4 * 4);
        }
#pragma unroll
        for (int i = 0; i < 4; ++i) {
            int idx = i * 256 + t;
            int fr = idx >> 4, c8 = idx & 15;  // 16 uint4 per f-row
            rb[i] = *(const uint4*)(Tb + (size_t)fr * NN + k0 + c8 * 8);
        }
    };

    auto writeLDS = [&](int bufi) {
        unsigned short* pA = sA[bufi];
        unsigned short* pB = sB[bufi];
#pragma unroll
        for (int i = 0; i < 8; ++i) {
            int idx = i * 256 + t;
            int row = idx >> 5, c4 = idx & 31;
            unsigned int byte = (unsigned)(row * 256 + c4 * 8);
            byte ^= (unsigned)((row & 15) << 4);  // swizzle, keeps 8B alignment
            ushort4 w;
            w.x = f2bf(ra[i].x);
            w.y = f2bf(ra[i].y);
            w.z = f2bf(ra[i].z);
            w.w = f2bf(ra[i].w);
            *(ushort4*)((char*)pA + byte) = w;
        }
#pragma unroll
        for (int i = 0; i < 4; ++i) {
            int idx = i * 256 + t;
            int fr = idx >> 4, c8 = idx & 15;
            unsigned int byte = (unsigned)(fr * 256 + c8 * 16);
            byte ^= (unsigned)((fr & 15) << 4);
            *(uint4*)((char*)pB + byte) = rb[i];
        }
    };

    // fragment addresses (A: row = lane&31 of wave's 32-row block; k = ks*16 + (lane>>5)*8)
    int arow = wm * 32 + (lane & 31);
    unsigned aBase = (unsigned)(arow * 256);
    unsigned aswz = (unsigned)((arow & 15) << 4);
    int frow = wf * 32 + (lane & 31);
    unsigned bBase = (unsigned)(frow * 256);
    unsigned bswz = (unsigned)((frow & 15) << 4);
    unsigned kh = (unsigned)((lane >> 5) * 16);  // byte offset of 8-bf16 half

    f32x16 acc = {};

    loadTiles(0);
    writeLDS(0);
    __syncthreads();

    for (int s = 0; s < NSTEP; ++s) {
        int cur = s & 1;
        if (s + 1 < NSTEP) loadTiles(s + 1);  // issue early, consumed after MFMAs
        const char* pA = (const char*)sA[cur];
        const char* pB = (const char*)sB[cur];
#pragma unroll
        for (int ks = 0; ks < 8; ++ks) {
            unsigned ab = (aBase + (unsigned)(ks * 32) + kh) ^ aswz;
            unsigned bb = (bBase + (unsigned)(ks * 32) + kh) ^ bswz;
            bf16x8 af = *(const bf16x8*)(pA + ab);
            bf16x8 bfr = *(const bf16x8*)(pB + bb);
            acc = __builtin_amdgcn_mfma_f32_32x32x16_bf16(af, bfr, acc, 0, 0, 0);
        }
        if (s + 1 < NSTEP) writeLDS((s + 1) & 1);  // other buffer; safe before barrier
        __syncthreads();
    }

    // epilogue: D col = lane&31 (f), row = (reg&3) + 8*(reg>>2) + 4*(lane>>5)
    float bv = bias[wf * 32 + (lane & 31)];
    float* ob = out + ((size_t)(b * NN + n0 + wm * 32)) * FF + wf * 32 + (lane & 31);
    int rbase = (lane >> 5) * 4;
#pragma unroll
    for (int r = 0; r < 16; ++r) {
        int rowl = (r & 3) + 8 * (r >> 2) + rbase;
        ob[(size_t)rowl * FF] = acc[r] + bv;
    }
}

extern "C" void kernel_launch(void* const* d_in, const int* in_sizes, int n_in,
                              void* d_out, int out_size, void* d_ws, size_t ws_size,
                              hipStream_t stream) {
    const float* adj = (const float*)d_in[0];
    const float* ann = (const float*)d_in[1];
    const float* bias = (const float*)d_in[2];
    float* out = (float*)d_out;
    unsigned short* annT = (unsigned short*)d_ws;  // 8*64*4096*2 = 4 MiB

    annT_kernel<<<dim3(8 * (NN / 64)), dim3(256), 0, stream>>>(ann, annT);
    gconv_kernel<<<dim3(8 * (NN / BM)), dim3(256), 0, stream>>>(adj, annT, bias, out);
}